// Round 1
// baseline (1150.896 us; speedup 1.0000x reference)
//
#include <hip/hip_runtime.h>

typedef float   f32x4 __attribute__((ext_vector_type(4)));
typedef _Float16 f16x8 __attribute__((ext_vector_type(8)));
typedef short   s16x8 __attribute__((ext_vector_type(8)));
typedef unsigned short u16;

#define NTOK 8192
#define CDIM 2048
#define NEXP 8
#define NASS 16384   // NTOK * TOP_K

#define GLOBAL_AS __attribute__((address_space(1)))
#define LDS_AS    __attribute__((address_space(3)))

__device__ __forceinline__ u16 f2h_bits(float f) {
  _Float16 h = (_Float16)f;
  union { _Float16 h; u16 u; } v;
  v.h = h;
  return v.u;
}

// ---------- router: fp32 logits, top-2, softmax, counts, x -> f16 ----------
__global__ __launch_bounds__(256) void moe_router(
    const float* __restrict__ x, const float* __restrict__ wr,
    u16* __restrict__ xh, int* __restrict__ top_idx,
    float* __restrict__ top_p, int* __restrict__ counts)
{
  const int wave = threadIdx.x >> 6, lane = threadIdx.x & 63;
  const int n = blockIdx.x * 4 + wave;            // one wave per token
  const float* xr = x + (size_t)n * CDIM;
  u16* xhr = xh + (size_t)n * CDIM;
  float acc[NEXP] = {};
  for (int i = 0; i < CDIM / 64; ++i) {
    const int c = i * 64 + lane;
    const float xv = xr[c];
    xhr[c] = f2h_bits(xv);                        // fused x -> f16
    const f32x4 w0 = *(const f32x4*)(wr + (size_t)c * NEXP);
    const f32x4 w1 = *(const f32x4*)(wr + (size_t)c * NEXP + 4);
    #pragma unroll
    for (int e = 0; e < 4; ++e) { acc[e] += xv * w0[e]; acc[4 + e] += xv * w1[e]; }
  }
  #pragma unroll
  for (int off = 32; off > 0; off >>= 1) {
    #pragma unroll
    for (int e = 0; e < NEXP; ++e) acc[e] += __shfl_xor(acc[e], off);
  }
  if (lane == 0) {
    int i0 = 0; float v0 = acc[0];
    #pragma unroll
    for (int e = 1; e < NEXP; ++e) { if (acc[e] > v0) { v0 = acc[e]; i0 = e; } }
    int i1 = -1; float v1 = -3.4e38f;
    #pragma unroll
    for (int e = 0; e < NEXP; ++e) { if (e != i0 && acc[e] > v1) { v1 = acc[e]; i1 = e; } }
    const float ex = __expf(v1 - v0);             // softmax over the 2 kept logits
    const float p0 = 1.f / (1.f + ex);
    top_idx[n * 2 + 0] = i0; top_idx[n * 2 + 1] = i1;
    top_p[n * 2 + 0] = p0;   top_p[n * 2 + 1] = 1.f - p0;
    atomicAdd(&counts[i0], 1);
    atomicAdd(&counts[i1], 1);
  }
}

// ---------- exclusive scan of 8 counts ----------
__global__ void moe_offsets(const int* __restrict__ counts,
                            int* __restrict__ offs, int* __restrict__ fill)
{
  if (threadIdx.x == 0) {
    int s = 0;
    for (int e = 0; e < NEXP; ++e) { offs[e] = s; fill[e] = s; s += counts[e]; }
    offs[NEXP] = s;
  }
}

// ---------- scatter (token, prob) into expert buckets ----------
__global__ __launch_bounds__(256) void moe_scatter(
    const int* __restrict__ top_idx, const float* __restrict__ top_p,
    int* fill, int* __restrict__ tok_s, float* __restrict__ prb_s)
{
  const int n = blockIdx.x * 256 + threadIdx.x;
  #pragma unroll
  for (int k = 0; k < 2; ++k) {
    const int e = top_idx[n * 2 + k];
    const int pos = atomicAdd(&fill[e], 1);
    tok_s[pos] = n;
    prb_s[pos] = top_p[n * 2 + k];
  }
}

// ---------- transpose+convert: w [E][K][N] fp32 -> wT [E][N][K] f16 ----------
__global__ __launch_bounds__(256) void moe_transpose(
    const float* __restrict__ wfc, const float* __restrict__ wpj,
    u16* __restrict__ wfcT, u16* __restrict__ wpjT)
{
  const float* src = blockIdx.z ? wpj : wfc;
  u16* dst = blockIdx.z ? wpjT : wfcT;
  const int e = blockIdx.y;
  src += (size_t)e * CDIM * CDIM;
  dst += (size_t)e * CDIM * CDIM;
  const int tr = (blockIdx.x >> 5) * 64;   // src row (K) base
  const int tc = (blockIdx.x & 31) * 64;   // src col (N) base
  __shared__ float lds[64][65];            // +1 pad breaks bank conflicts
  const int t = threadIdx.x;
  #pragma unroll
  for (int p = 0; p < 4; ++p) {
    const int r  = p * 16 + (t >> 4);
    const int c4 = (t & 15) * 4;
    const f32x4 v = *(const f32x4*)(src + (size_t)(tr + r) * CDIM + tc + c4);
    #pragma unroll
    for (int j = 0; j < 4; ++j) lds[r][c4 + j] = v[j];
  }
  __syncthreads();
  const int d  = t >> 2;
  const int cs = (t & 3) * 16;
  s16x8 o0, o1;
  #pragma unroll
  for (int j = 0; j < 8; ++j) o0[j] = (short)f2h_bits(lds[cs + j][d]);
  #pragma unroll
  for (int j = 0; j < 8; ++j) o1[j] = (short)f2h_bits(lds[cs + 8 + j][d]);
  u16* drow = dst + (size_t)(tc + d) * CDIM + tr + cs;
  *(s16x8*)(drow + 0) = o0;
  *(s16x8*)(drow + 8) = o1;
}

// ---------- grouped GEMM, m97 structure + T2 source-swizzle ----------
// MODE 0: H[s,:] = f16(relu(Xg @ WfcT^T)^2)   (A = xh gathered via tok_s)
// MODE 1: out[tok,:] += prb * (H @ WpjT^T)    (A = h linear; atomic combine)
template<int MODE>
__global__ __launch_bounds__(256) void moe_gemm(
    const u16* __restrict__ A, const u16* __restrict__ W,
    const int* __restrict__ tok_s, const float* __restrict__ prb_s,
    const int* __restrict__ offs, u16* __restrict__ hout,
    float* __restrict__ out)
{
  const int e     = blockIdx.x >> 6;
  const int mtile = blockIdx.x & 63;
  const int off0  = offs[e];
  const int Me    = offs[e + 1] - off0;
  const int m0    = mtile * 128;
  if (m0 >= Me) return;
  const int n0 = blockIdx.y * 128;
  const u16* We = W + (size_t)e * CDIM * CDIM;

  __shared__ u16 As[128 * 64];
  __shared__ u16 Bs[128 * 64];

  const int t = threadIdx.x;
  const int lane = t & 63, wave = t >> 6;
  const int wm = wave >> 1, wn = wave & 1;
  const int arow = lane >> 3;                          // row within 8-row segment
  // T2: involutive chunk swizzle (chunk ^= row&7); LDS stays linear for
  // global_load_lds, the GLOBAL source column is pre-permuted instead.
  const int acol = (((lane & 7) ^ arow) * 8);          // element col within BK=64

  const u16* asrc[4];
  const u16* bsrc[4];
  #pragma unroll
  for (int i = 0; i < 4; ++i) {
    const int seg = i * 4 + wave;
    const int r = seg * 8 + arow;
    const int rr = (m0 + r < Me) ? (m0 + r) : (Me - 1);      // clamp tail rows
    const int grow = (MODE == 0) ? tok_s[off0 + rr] : (off0 + rr);
    asrc[i] = A  + (size_t)grow * CDIM + acol;
    bsrc[i] = We + (size_t)(n0 + r) * CDIM + acol;
  }

  f32x4 acc[4][4] = {};

  for (int k0 = 0; k0 < CDIM; k0 += 64) {
    #pragma unroll
    for (int i = 0; i < 4; ++i) {
      const int seg = i * 4 + wave;
      __builtin_amdgcn_global_load_lds(
          (const GLOBAL_AS void*)(asrc[i] + k0),
          (LDS_AS void*)&As[seg * 8 * 64], 16, 0, 0);
      __builtin_amdgcn_global_load_lds(
          (const GLOBAL_AS void*)(bsrc[i] + k0),
          (LDS_AS void*)&Bs[seg * 8 * 64], 16, 0, 0);
    }
    __syncthreads();
    const int rsel = lane & 15;
    const int rs7  = rsel & 7;
    const int g    = lane >> 4;
    #pragma unroll
    for (int ks = 0; ks < 2; ++ks) {
      f16x8 av[4], bv[4];
      const int ch = (ks * 4 + g) ^ rs7;               // swizzled read chunk
      #pragma unroll
      for (int fm = 0; fm < 4; ++fm)
        av[fm] = *(const f16x8*)&As[(wm * 64 + fm * 16 + rsel) * 64 + ch * 8];
      #pragma unroll
      for (int fn = 0; fn < 4; ++fn)
        bv[fn] = *(const f16x8*)&Bs[(wn * 64 + fn * 16 + rsel) * 64 + ch * 8];
      #pragma unroll
      for (int fm = 0; fm < 4; ++fm)
        #pragma unroll
        for (int fn = 0; fn < 4; ++fn)
          acc[fm][fn] = __builtin_amdgcn_mfma_f32_16x16x32_f16(
              av[fm], bv[fn], acc[fm][fn], 0, 0, 0);
    }
    __syncthreads();
  }

  const int crow = (lane >> 4) * 4;    // C/D: col = lane&15, row = (lane>>4)*4 + j
  const int ccol = lane & 15;
  #pragma unroll
  for (int fm = 0; fm < 4; ++fm) {
    #pragma unroll
    for (int j = 0; j < 4; ++j) {
      const int r = m0 + wm * 64 + fm * 16 + crow + j;
      if (r >= Me) continue;
      const int s = off0 + r;
      if (MODE == 0) {
        u16* hr = hout + (size_t)s * CDIM;
        #pragma unroll
        for (int fn = 0; fn < 4; ++fn) {
          float v = acc[fm][fn][j];
          v = v > 0.f ? v * v : 0.f;                  // relu^2 fused
          hr[n0 + wn * 64 + fn * 16 + ccol] = f2h_bits(v);
        }
      } else {
        const float p = prb_s[s];
        float* orow = out + (size_t)tok_s[s] * CDIM;
        #pragma unroll
        for (int fn = 0; fn < 4; ++fn)
          atomicAdd(&orow[n0 + wn * 64 + fn * 16 + ccol], p * acc[fm][fn][j]);
      }
    }
  }
}

extern "C" void kernel_launch(void* const* d_in, const int* in_sizes, int n_in,
                              void* d_out, int out_size, void* d_ws, size_t ws_size,
                              hipStream_t stream)
{
  const float* x   = (const float*)d_in[0];
  const float* wr  = (const float*)d_in[1];
  const float* wfc = (const float*)d_in[2];
  const float* wpj = (const float*)d_in[3];
  float* out = (float*)d_out;
  char* ws = (char*)d_ws;

  const size_t OFF_TIDX = 256;
  const size_t OFF_TP   = OFF_TIDX + (size_t)NASS * 4;
  const size_t OFF_TOK  = OFF_TP   + (size_t)NASS * 4;
  const size_t OFF_PRB  = OFF_TOK  + (size_t)NASS * 4;
  const size_t OFF_XH   = (size_t)1 << 20;
  const size_t OFF_WFCT = OFF_XH   + (size_t)NTOK * CDIM * 2;
  const size_t OFF_WPJT = OFF_WFCT + (size_t)NEXP * CDIM * CDIM * 2;
  const size_t OFF_H    = OFF_WPJT + (size_t)NEXP * CDIM * CDIM * 2;
  const size_t NEED     = OFF_H    + (size_t)NASS * CDIM * 2;   // 235,929,600 B

  if (ws_size < NEED) {            // signal: absmax == |ref|max means ws too small
    hipMemsetAsync(d_out, 0, (size_t)out_size * 4, stream);
    return;
  }

  int*   counts = (int*)(ws + 0);
  int*   offs   = (int*)(ws + 64);
  int*   fill   = (int*)(ws + 128);
  int*   tidx   = (int*)(ws + OFF_TIDX);
  float* tp     = (float*)(ws + OFF_TP);
  int*   tok    = (int*)(ws + OFF_TOK);
  float* prb    = (float*)(ws + OFF_PRB);
  u16*   xh     = (u16*)(ws + OFF_XH);
  u16*   wfcT   = (u16*)(ws + OFF_WFCT);
  u16*   wpjT   = (u16*)(ws + OFF_WPJT);
  u16*   h      = (u16*)(ws + OFF_H);

  hipMemsetAsync(ws, 0, 256, stream);                       // counts/fill
  hipMemsetAsync(d_out, 0, (size_t)out_size * 4, stream);   // atomic target

  moe_router  <<<NTOK / 4, 256, 0, stream>>>(x, wr, xh, tidx, tp, counts);
  moe_offsets <<<1, 64, 0, stream>>>(counts, offs, fill);
  moe_scatter <<<NTOK / 256, 256, 0, stream>>>(tidx, tp, fill, tok, prb);
  moe_transpose<<<dim3(1024, NEXP, 2), 256, 0, stream>>>(wfc, wpj, wfcT, wpjT);
  moe_gemm<0><<<dim3(NEXP * 64, 16), 256, 0, stream>>>(xh, wfcT, tok, nullptr, offs, h, nullptr);
  moe_gemm<1><<<dim3(NEXP * 64, 16), 256, 0, stream>>>(h,  wpjT, tok, prb,     offs, nullptr, out);
}

// Round 2
// 884.660 us; speedup vs baseline: 1.3009x; 1.3009x over previous
//
#include <hip/hip_runtime.h>

typedef float   f32x4 __attribute__((ext_vector_type(4)));
typedef _Float16 f16x8 __attribute__((ext_vector_type(8)));
typedef short   s16x8 __attribute__((ext_vector_type(8)));
typedef unsigned short u16;

#define NTOK 8192
#define CDIM 2048
#define NEXP 8
#define NASS 16384   // NTOK * TOP_K

#define GLOBAL_AS __attribute__((address_space(1)))
#define LDS_AS    __attribute__((address_space(3)))

__device__ __forceinline__ u16 f2h_bits(float f) {
  _Float16 h = (_Float16)f;
  union { _Float16 h; u16 u; } v;
  v.h = h;
  return v.u;
}

// ---------- router: fp32 logits, top-2, softmax, counts, x -> f16 ----------
__global__ __launch_bounds__(256) void moe_router(
    const float* __restrict__ x, const float* __restrict__ wr,
    u16* __restrict__ xh, int* __restrict__ top_idx,
    float* __restrict__ top_p, int* __restrict__ counts)
{
  const int wave = threadIdx.x >> 6, lane = threadIdx.x & 63;
  const int n = blockIdx.x * 4 + wave;            // one wave per token
  const float* xr = x + (size_t)n * CDIM;
  u16* xhr = xh + (size_t)n * CDIM;
  float acc[NEXP] = {};
  for (int i = 0; i < CDIM / 64; ++i) {
    const int c = i * 64 + lane;
    const float xv = xr[c];
    xhr[c] = f2h_bits(xv);                        // fused x -> f16
    const f32x4 w0 = *(const f32x4*)(wr + (size_t)c * NEXP);
    const f32x4 w1 = *(const f32x4*)(wr + (size_t)c * NEXP + 4);
    #pragma unroll
    for (int e = 0; e < 4; ++e) { acc[e] += xv * w0[e]; acc[4 + e] += xv * w1[e]; }
  }
  #pragma unroll
  for (int off = 32; off > 0; off >>= 1) {
    #pragma unroll
    for (int e = 0; e < NEXP; ++e) acc[e] += __shfl_xor(acc[e], off);
  }
  if (lane == 0) {
    int i0 = 0; float v0 = acc[0];
    #pragma unroll
    for (int e = 1; e < NEXP; ++e) { if (acc[e] > v0) { v0 = acc[e]; i0 = e; } }
    int i1 = -1; float v1 = -3.4e38f;
    #pragma unroll
    for (int e = 0; e < NEXP; ++e) { if (e != i0 && acc[e] > v1) { v1 = acc[e]; i1 = e; } }
    const float ex = __expf(v1 - v0);             // softmax over the 2 kept logits
    const float p0 = 1.f / (1.f + ex);
    top_idx[n * 2 + 0] = i0; top_idx[n * 2 + 1] = i1;
    top_p[n * 2 + 0] = p0;   top_p[n * 2 + 1] = 1.f - p0;
    atomicAdd(&counts[i0], 1);
    atomicAdd(&counts[i1], 1);
  }
}

// ---------- exclusive scan of 8 counts ----------
__global__ void moe_offsets(const int* __restrict__ counts,
                            int* __restrict__ offs, int* __restrict__ fill)
{
  if (threadIdx.x == 0) {
    int s = 0;
    for (int e = 0; e < NEXP; ++e) { offs[e] = s; fill[e] = s; s += counts[e]; }
    offs[NEXP] = s;
  }
}

// ---------- scatter (token, prob) into expert buckets ----------
__global__ __launch_bounds__(256) void moe_scatter(
    const int* __restrict__ top_idx, const float* __restrict__ top_p,
    int* fill, int* __restrict__ tok_s, float* __restrict__ prb_s)
{
  const int n = blockIdx.x * 256 + threadIdx.x;
  #pragma unroll
  for (int k = 0; k < 2; ++k) {
    const int e = top_idx[n * 2 + k];
    const int pos = atomicAdd(&fill[e], 1);
    tok_s[pos] = n;
    prb_s[pos] = top_p[n * 2 + k];
  }
}

// ---------- transpose+convert: w [E][K][N] fp32 -> wT [E][N][K] f16 ----------
__global__ __launch_bounds__(256) void moe_transpose(
    const float* __restrict__ wfc, const float* __restrict__ wpj,
    u16* __restrict__ wfcT, u16* __restrict__ wpjT)
{
  const float* src = blockIdx.z ? wpj : wfc;
  u16* dst = blockIdx.z ? wpjT : wfcT;
  const int e = blockIdx.y;
  src += (size_t)e * CDIM * CDIM;
  dst += (size_t)e * CDIM * CDIM;
  const int tr = (blockIdx.x >> 5) * 64;   // src row (K) base
  const int tc = (blockIdx.x & 31) * 64;   // src col (N) base
  __shared__ float lds[64][65];            // +1 pad breaks bank conflicts
  const int t = threadIdx.x;
  #pragma unroll
  for (int p = 0; p < 4; ++p) {
    const int r  = p * 16 + (t >> 4);
    const int c4 = (t & 15) * 4;
    const f32x4 v = *(const f32x4*)(src + (size_t)(tr + r) * CDIM + tc + c4);
    #pragma unroll
    for (int j = 0; j < 4; ++j) lds[r][c4 + j] = v[j];
  }
  __syncthreads();
  const int d  = t >> 2;
  const int cs = (t & 3) * 16;
  s16x8 o0, o1;
  #pragma unroll
  for (int j = 0; j < 8; ++j) o0[j] = (short)f2h_bits(lds[cs + j][d]);
  #pragma unroll
  for (int j = 0; j < 8; ++j) o1[j] = (short)f2h_bits(lds[cs + 8 + j][d]);
  u16* drow = dst + (size_t)(tc + d) * CDIM + tr + cs;
  *(s16x8*)(drow + 0) = o0;
  *(s16x8*)(drow + 8) = o1;
}

// ---------- grouped GEMM: 256x256 tile, BK=64, 8 waves, dbuf + counted vmcnt ----------
// MODE 0: H[s,:] = f16(relu(Xg @ WfcT^T)^2)   (A = xh gathered via tok_s)
// MODE 1: out[tok,:] += prb * (H @ WpjT^T)    (A = h linear; atomic combine)
template<int MODE>
__global__ __launch_bounds__(512, 2) void moe_gemm2(
    const u16* __restrict__ A, const u16* __restrict__ W,
    const int* __restrict__ tok_s, const float* __restrict__ prb_s,
    const int* __restrict__ offs, u16* __restrict__ hout,
    float* __restrict__ out)
{
  const int e     = blockIdx.y >> 5;          // 32 m-tiles per expert (Me <= 8192)
  const int mtile = blockIdx.y & 31;
  const int off0  = offs[e];
  const int Me    = offs[e + 1] - off0;
  const int m0    = mtile * 256;
  if (m0 >= Me) return;
  const int n0 = blockIdx.x * 256;
  const u16* We = W + (size_t)e * CDIM * CDIM;

  __shared__ u16 As[2][256 * 64];   // 32 KB x2
  __shared__ u16 Bs[2][256 * 64];   // 32 KB x2   -> 128 KB total

  const int t    = threadIdx.x;
  const int lane = t & 63, wv = t >> 6;       // 8 waves
  const int wm = wv >> 2, wn = wv & 3;        // wave tile: rows wm*128, cols wn*64

  // Staging: wave wv stages rows [wv*32, wv*32+32) of both A and B tiles.
  // T2 swizzle via pre-swizzled GLOBAL source (LDS dest stays linear).
  const int arow8 = lane >> 3;                         // 0..7
  const int acol  = (((lane & 7) ^ arow8) * 8);        // swizzled k-chunk * 8
  const u16* asrc[4];
  const u16* bsrc[4];
  #pragma unroll
  for (int i = 0; i < 4; ++i) {
    const int r  = wv * 32 + i * 8 + arow8;            // 0..255
    const int mr = m0 + r;
    const int rr = (mr < Me) ? mr : (Me - 1);          // clamp tail rows
    const int ga = (MODE == 0) ? tok_s[off0 + rr] : (off0 + rr);
    asrc[i] = A  + (size_t)ga * CDIM + acol;
    bsrc[i] = We + (size_t)(n0 + r) * CDIM + acol;
  }

  #define STAGE(tt, bb)                                                        \
    { const int kk = (tt) * 64;                                                \
      _Pragma("unroll")                                                        \
      for (int i = 0; i < 4; ++i) {                                            \
        __builtin_amdgcn_global_load_lds(                                      \
            (const GLOBAL_AS void*)(asrc[i] + kk),                             \
            (LDS_AS void*)&As[bb][(wv * 32 + i * 8) * 64], 16, 0, 0);          \
        __builtin_amdgcn_global_load_lds(                                      \
            (const GLOBAL_AS void*)(bsrc[i] + kk),                             \
            (LDS_AS void*)&Bs[bb][(wv * 32 + i * 8) * 64], 16, 0, 0);          \
      } }

  f32x4 acc[8][4] = {};
  const int rsel = lane & 15;
  const int rs7  = rsel & 7;
  const int g    = lane >> 4;

  #define COMPUTE(bb)                                                          \
    { _Pragma("unroll")                                                        \
      for (int ks = 0; ks < 2; ++ks) {                                         \
        const int ch = (ks * 4 + g) ^ rs7;                                     \
        f16x8 bv[4];                                                           \
        _Pragma("unroll")                                                      \
        for (int fn = 0; fn < 4; ++fn)                                         \
          bv[fn] = *(const f16x8*)&Bs[bb][(wn * 64 + fn * 16 + rsel) * 64 + ch * 8]; \
        _Pragma("unroll")                                                      \
        for (int mh = 0; mh < 2; ++mh) {                                       \
          f16x8 av[4];                                                         \
          _Pragma("unroll")                                                    \
          for (int fi = 0; fi < 4; ++fi)                                       \
            av[fi] = *(const f16x8*)&As[bb][(wm * 128 + mh * 64 + fi * 16 + rsel) * 64 + ch * 8]; \
          _Pragma("unroll")                                                    \
          for (int fi = 0; fi < 4; ++fi)                                       \
            _Pragma("unroll")                                                  \
            for (int fn = 0; fn < 4; ++fn)                                     \
              acc[mh * 4 + fi][fn] = __builtin_amdgcn_mfma_f32_16x16x32_f16(   \
                  av[fi], bv[fn], acc[mh * 4 + fi][fn], 0, 0, 0);              \
        }                                                                      \
      } }

  // Pipeline: stage(t+1) issued before computing t; vmcnt(8) leaves the
  // prefetch (8 insts/wave) in flight across the barrier -> latency hidden
  // under the full-tile compute (~2.4k cyc >> HBM ~900 cyc).
  STAGE(0, 0);
  for (int tt = 0; tt < 31; ++tt) {
    STAGE(tt + 1, (tt + 1) & 1);
    asm volatile("s_waitcnt vmcnt(8)" ::: "memory");   // tile tt landed
    __builtin_amdgcn_s_barrier();
    COMPUTE(tt & 1);
    __builtin_amdgcn_s_barrier();                      // reads done before next overwrite
  }
  asm volatile("s_waitcnt vmcnt(0)" ::: "memory");     // tile 31 landed
  __builtin_amdgcn_s_barrier();
  COMPUTE(1);

  #undef STAGE
  #undef COMPUTE

  // Epilogue. C/D map: col = lane&15, row = (lane>>4)*4 + j.
  const int crow = g * 4;
  const int ccol = rsel;
  #pragma unroll
  for (int mh = 0; mh < 2; ++mh) {
    #pragma unroll
    for (int fi = 0; fi < 4; ++fi) {
      #pragma unroll
      for (int j = 0; j < 4; ++j) {
        const int r = m0 + wm * 128 + mh * 64 + fi * 16 + crow + j;
        if (r >= Me) continue;
        const int s = off0 + r;
        if (MODE == 0) {
          u16* hr = hout + (size_t)s * CDIM;
          #pragma unroll
          for (int fn = 0; fn < 4; ++fn) {
            float v = acc[mh * 4 + fi][fn][j];
            v = v > 0.f ? v * v : 0.f;                 // relu^2 fused
            hr[n0 + wn * 64 + fn * 16 + ccol] = f2h_bits(v);
          }
        } else {
          const float p = prb_s[s];
          float* orow = out + (size_t)tok_s[s] * CDIM;
          #pragma unroll
          for (int fn = 0; fn < 4; ++fn)
            atomicAdd(&orow[n0 + wn * 64 + fn * 16 + ccol], p * acc[mh * 4 + fi][fn][j]);
        }
      }
    }
  }
}

extern "C" void kernel_launch(void* const* d_in, const int* in_sizes, int n_in,
                              void* d_out, int out_size, void* d_ws, size_t ws_size,
                              hipStream_t stream)
{
  const float* x   = (const float*)d_in[0];
  const float* wr  = (const float*)d_in[1];
  const float* wfc = (const float*)d_in[2];
  const float* wpj = (const float*)d_in[3];
  float* out = (float*)d_out;
  char* ws = (char*)d_ws;

  const size_t OFF_TIDX = 256;
  const size_t OFF_TP   = OFF_TIDX + (size_t)NASS * 4;
  const size_t OFF_TOK  = OFF_TP   + (size_t)NASS * 4;
  const size_t OFF_PRB  = OFF_TOK  + (size_t)NASS * 4;
  const size_t OFF_XH   = (size_t)1 << 20;
  const size_t OFF_WFCT = OFF_XH   + (size_t)NTOK * CDIM * 2;
  const size_t OFF_WPJT = OFF_WFCT + (size_t)NEXP * CDIM * CDIM * 2;
  const size_t OFF_H    = OFF_WPJT + (size_t)NEXP * CDIM * CDIM * 2;
  const size_t NEED     = OFF_H    + (size_t)NASS * CDIM * 2;   // ~236 MB

  if (ws_size < NEED) {            // signal: absmax == |ref|max means ws too small
    hipMemsetAsync(d_out, 0, (size_t)out_size * 4, stream);
    return;
  }

  int*   counts = (int*)(ws + 0);
  int*   offs   = (int*)(ws + 64);
  int*   fill   = (int*)(ws + 128);
  int*   tidx   = (int*)(ws + OFF_TIDX);
  float* tp     = (float*)(ws + OFF_TP);
  int*   tok    = (int*)(ws + OFF_TOK);
  float* prb    = (float*)(ws + OFF_PRB);
  u16*   xh     = (u16*)(ws + OFF_XH);
  u16*   wfcT   = (u16*)(ws + OFF_WFCT);
  u16*   wpjT   = (u16*)(ws + OFF_WPJT);
  u16*   h      = (u16*)(ws + OFF_H);

  hipMemsetAsync(ws, 0, 256, stream);                       // counts/fill
  hipMemsetAsync(d_out, 0, (size_t)out_size * 4, stream);   // atomic target

  moe_router  <<<NTOK / 4, 256, 0, stream>>>(x, wr, xh, tidx, tp, counts);
  moe_offsets <<<1, 64, 0, stream>>>(counts, offs, fill);
  moe_scatter <<<NTOK / 256, 256, 0, stream>>>(tidx, tp, fill, tok, prb);
  moe_transpose<<<dim3(1024, NEXP, 2), 256, 0, stream>>>(wfc, wpj, wfcT, wpjT);
  moe_gemm2<0><<<dim3(8, NEXP * 32), 512, 0, stream>>>(xh, wfcT, tok, nullptr, offs, h, nullptr);
  moe_gemm2<1><<<dim3(8, NEXP * 32), 512, 0, stream>>>(h,  wpjT, tok, prb,     offs, nullptr, out);
}